// Round 7
// baseline (635.057 us; speedup 1.0000x reference)
//
#include <hip/hip_runtime.h>
#include <utility>
#include <cstddef>

// ---------------- compile-time Ivanic-Ruedenberg tables ----------------

struct Term { int o; int r; int a; float c; };
struct LTable { int n; Term t[1024]; };

constexpr double csqrt(double x) {
    if (x <= 0.0) return 0.0;
    double g = x < 1.0 ? 1.0 : x;
    for (int i = 0; i < 50; ++i) g = 0.5 * (g + x / g);
    return g;
}
constexpr int cabs_i(int x) { return x < 0 ? -x : x; }
constexpr int cmax_i(int a, int b) { return a > b ? a : b; }

constexpr void add_p(LTable& T, int o, double scale, int i, int a, int b, int l) {
    int lp = l - 1;
    int np = 2 * lp + 1;
    int row = i + 1;
    if (b == l) {
        T.t[T.n++] = Term{o, row * 3 + 2, (a + lp) * np + 2 * lp, (float)scale};
        T.t[T.n++] = Term{o, row * 3 + 0, (a + lp) * np + 0,      (float)(-scale)};
    } else if (b == -l) {
        T.t[T.n++] = Term{o, row * 3 + 2, (a + lp) * np + 0,      (float)scale};
        T.t[T.n++] = Term{o, row * 3 + 0, (a + lp) * np + 2 * lp, (float)scale};
    } else {
        T.t[T.n++] = Term{o, row * 3 + 1, (a + lp) * np + (b + lp), (float)scale};
    }
}

constexpr LTable ru_table(int l) {
    LTable T{};
    int n = 2 * l + 1;
    for (int m = -l; m <= l; ++m) {
        for (int mp = -l; mp <= l; ++mp) {
            double denom = (cabs_i(mp) == l) ? (double)((2 * l) * (2 * l - 1))
                                             : (double)((l + mp) * (l - mp));
            double d0 = (m == 0) ? 1.0 : 0.0;
            double u = csqrt((double)((l + m) * (l - m)) / denom);
            double v = 0.5 * csqrt((1.0 + d0) * (l + cabs_i(m) - 1) * (l + cabs_i(m)) / denom)
                       * (1.0 - 2.0 * d0);
            double w = -0.5 * csqrt((double)cmax_i(l - cabs_i(m) - 1, 0) * (l - cabs_i(m)) / denom)
                       * (1.0 - d0);
            int o = (m + l) * n + (mp + l);
            if (u != 0.0) add_p(T, o, u, 0, m, mp, l);
            if (v != 0.0) {
                if (m == 0) {
                    add_p(T, o, v, 1, 1, mp, l);
                    add_p(T, o, v, -1, -1, mp, l);
                } else if (m > 0) {
                    double s = (m == 1) ? csqrt(2.0) : 1.0;
                    add_p(T, o, v * s, 1, m - 1, mp, l);
                    if (m != 1) add_p(T, o, -v, -1, -m + 1, mp, l);
                } else {
                    if (m != -1) add_p(T, o, v, 1, m + 1, mp, l);
                    double s = (m == -1) ? csqrt(2.0) : 1.0;
                    add_p(T, o, v * s, -1, -m - 1, mp, l);
                }
            }
            if (w != 0.0) {
                if (m > 0) {
                    add_p(T, o, w, 1, m + 1, mp, l);
                    add_p(T, o, w, -1, -m - 1, mp, l);
                } else {
                    add_p(T, o, w, 1, m - 1, mp, l);
                    add_p(T, o, -w, -1, -m + 1, mp, l);
                }
            }
        }
    }
    return T;
}

inline constexpr LTable T2 = ru_table(2);
inline constexpr LTable T3 = ru_table(3);
inline constexpr LTable T4 = ru_table(4);

// terms for a given output entry are contiguous by construction (m-major, mp-minor)
template<const LTable& T>
constexpr int er_start(int e) {
    for (int i = 0; i < T.n; ++i) if (T.t[i].o == e) return i;
    return 0;
}
template<const LTable& T>
constexpr int er_cnt(int e) {
    int c = 0;
    for (int i = 0; i < T.n; ++i) if (T.t[i].o == e) ++c;
    return c;
}

template<const LTable& T, int S, size_t... K>
__device__ __forceinline__ float sum_terms(const float* __restrict__ R1,
                                           const float* __restrict__ P,
                                           std::index_sequence<K...>) {
    float a = 0.0f;
    ((a = fmaf(T.t[S + (int)K].c, R1[T.t[S + (int)K].r] * P[T.t[S + (int)K].a], a)), ...);
    return a;
}

// compute one entry of block l, optionally keep in array, stream ds_write to row
template<const LTable& T, int l, bool KEEP, int e>
__device__ __forceinline__ void level_one(const float* __restrict__ R1,
                                          const float* __restrict__ P,
                                          float* __restrict__ keep,
                                          float* __restrict__ row) {
    constexpr int S = er_start<T>(e);
    constexpr int C = er_cnt<T>(e);
    float v = sum_terms<T, S>(R1, P, std::make_index_sequence<C>{});
    if constexpr (KEEP) keep[e] = v;
    constexpr int d = 2 * l + 1;
    constexpr int r = e / d, c = e % d;
    constexpr int E625 = (l * l + r) * 25 + (l * l + c);  // ds_write imm offset
    row[E625] = v;
}

template<const LTable& T, int l, bool KEEP, size_t... E>
__device__ __forceinline__ void level(const float* __restrict__ R1,
                                      const float* __restrict__ P,
                                      float* __restrict__ keep,
                                      float* __restrict__ row,
                                      std::index_sequence<E...>) {
    (level_one<T, l, KEEP, (int)E>(R1, P, keep, row), ...);
}

template<size_t... E>
__device__ __forceinline__ void write_l1(const float* __restrict__ D1,
                                         float* __restrict__ row,
                                         std::index_sequence<E...>) {
    ((row[(1 + (int)E / 3) * 25 + (1 + (int)E % 3)] = D1[E]), ...);
}

// native clang vector type: required by __builtin_nontemporal_store
typedef float v4f __attribute__((ext_vector_type(4)));

// ---------------- fused kernel, small tiles for generation packing ----------------
// Block: 256 threads, 64 points, 4 chunks of 16 points.
// Single LDS image 16x625 floats = 40,000 B -> 4 blocks/CU (1024 resident
// blocks; grid 3125 -> ~3 full generations + 2% tail, vs r5's 1.5 gens at
// 2 blocks/CU which idled half the device for a third of the time).
// Per chunk: the 16 owner threads recompute their D from 4 live trig regs and
// stream entries via compile-time-immediate ds_writes (bank = (17*p0+E)%32,
// injective over p0 -> conflict-free). Structural zeros written once.
// Copy phase: contiguous 16B-aligned nontemporal v4f, all 256 threads.
// __launch_bounds__(256,4): 4 waves/EU -> 128-VGPR cap; scatter peak liveness
// ~95 floats, no scratch.

__global__ __launch_bounds__(256, 4)
void wigner_fused_kernel(const float* __restrict__ xyz, float* __restrict__ out, int Ntot) {
    __shared__ float img[16 * 625];

    const int t = threadIdx.x;
    const int pblk = blockIdx.x * 64;
    const int gp = pblk + t;  // meaningful for t < 64 only

    float ct = 1.0f, st = 0.0f, cp = 1.0f, sp = 0.0f;
    if (t < 64 && gp < Ntot) {
        const float x = xyz[3 * gp + 0];
        const float y = xyz[3 * gp + 1];
        const float z = xyz[3 * gp + 2];
        // trig without trig: ct = vz (clipped), st = sqrt(1-ct^2), cp/sp from x,y
        const float r2 = x * x + y * y + z * z;
        const float rinv = rsqrtf(fmaxf(r2, 1e-24f));
        ct = fminf(fmaxf(z * rinv, -1.0f), 1.0f);
        st = sqrtf(fmaxf(1.0f - ct * ct, 0.0f));
        const float rxy2 = x * x + y * y;
        if (rxy2 > 0.0f) {
            const float ri = rsqrtf(rxy2);
            cp = x * ri;
            sp = y * ri;
        }
    }
    // only ct, st, cp, sp stay live across the chunk loop (4 VGPRs)

    // zero image once (zero-structure slots never rewritten)
    {
        v4f* b4 = (v4f*)img;
        const v4f z4 = {0.0f, 0.0f, 0.0f, 0.0f};
#pragma unroll 4
        for (int k = t; k < 2500; k += 256) b4[k] = z4;
    }
    __syncthreads();

    const int p0 = t & 15;
    const int own = t >> 4;  // for t<64: chunk index 0..3 of this thread's point
    const long long blk_f = (long long)pblk * 625;

#pragma unroll 1
    for (int c = 0; c < 4; ++c) {
        const int base_pt = pblk + c * 16;
        if (base_pt >= Ntot) break;  // uniform across block

        // scatter: 16 owner threads recompute D and stream into the image
        if (t < 64 && own == c && gp < Ntot) {
            float* __restrict__ row = img + p0 * 625;
            row[0] = 1.0f;  // l=0 block

            // R1 in real-SH l=1 basis order (y,z,x), row-major 3x3
            float D1[9] = {cp,      0.0f, -sp,
                           st * sp, ct,   st * cp,
                           ct * sp, -st,  ct * cp};
            write_l1(D1, row, std::make_index_sequence<9>{});

            float D2[25];
            level<T2, 2, true>(D1, D1, D2, row, std::make_index_sequence<25>{});
            float D3[49];
            level<T3, 3, true>(D1, D2, D3, row, std::make_index_sequence<49>{});
            level<T4, 4, false>(D1, D3, nullptr, row, std::make_index_sequence<81>{});
        }
        __syncthreads();

        const int vp = min(16, Ntot - base_pt);
        const long long out_f = blk_f + (long long)c * 16 * 625;
        if (vp == 16) {
            const v4f* src = (const v4f*)img;
            v4f* dst = (v4f*)(out + out_f);
            for (int k = t; k < 2500; k += 256) {
                __builtin_nontemporal_store(src[k], dst + k);
            }
        } else {
            const int vf = vp * 625;
            for (int k = t; k < vf; k += 256) {
                out[out_f + k] = img[k];
            }
        }
        __syncthreads();
    }
}

extern "C" void kernel_launch(void* const* d_in, const int* in_sizes, int n_in,
                              void* d_out, int out_size, void* d_ws, size_t ws_size,
                              hipStream_t stream) {
    const float* xyz = (const float*)d_in[0];
    float* out = (float*)d_out;
    const int N = in_sizes[0] / 3;
    const int blocks = (N + 63) / 64;
    hipLaunchKernelGGL(wigner_fused_kernel, dim3(blocks), dim3(256), 0, stream,
                       xyz, out, N);
}